// Round 11
// baseline (99.004 us; speedup 1.0000x reference)
//
#include <hip/hip_runtime.h>
#include <hip/hip_bf16.h>
#include <hip/hip_fp16.h>
#include <math.h>

#define N_NODES 50000
#define N_EDGES 800000
#define IN_DIM 128
#define OUT_DIM 64

typedef __attribute__((ext_vector_type(8))) short bf16x8;
typedef __attribute__((ext_vector_type(4))) float f32x4;

static __device__ __forceinline__ uint f2bf(float f) {
  uint u = __float_as_uint(f);
  return (u + 0x7fffu + ((u >> 16) & 1u)) >> 16;  // RNE
}

#define N4 (N_NODES / 4)            // 12500
#define SCAN_NB ((N4 + 255) / 256)  // 49
#define GEMM_NB ((N_NODES + 63) / 64)         // 782 tiles
#define K2_T (N_EDGES / 8)                    // 100000
#define K4_T (N_EDGES / 8)                    // 100000

// ---------------------------------------------------------------------------
// K0: zero deg + pack W into MFMA-fragment order (bf16):
// WTfrag[((nt*4+ks)*64+lane)*8+j] = bf16(W[k][c]), c=nt*16+(lane&15),
// k=ks*32+(lane>>4)*8+j  -> k1 B-load = wave-uniform base + lane*16B.
// ---------------------------------------------------------------------------
__global__ __launch_bounds__(256) void k0_prep(const float* __restrict__ W,
                                               int* __restrict__ deg,
                                               ushort* __restrict__ WTfrag) {
  int t = blockIdx.x * 256 + threadIdx.x;
  if (t < N4) ((int4*)deg)[t] = make_int4(0, 0, 0, 0);
  if (t < IN_DIM * OUT_DIM) {
    int j = t & 7, l = (t >> 3) & 63, ks = (t >> 9) & 3, nt = (t >> 11) & 3;
    int c = nt * 16 + (l & 15);
    int k = ks * 32 + ((l >> 4) << 3) + j;
    WTfrag[t] = (ushort)f2bf(W[(size_t)k * OUT_DIM + c]);
  }
}

// ---------------------------------------------------------------------------
// K1: h = x @ W, SINGLE-term bf16 MFMA (x-bf16 RNE noise ~3e-3 max vs 1.9e-2
// budget). A staged in 16KB LDS (XOR-swizzled); B from WTfrag (L1-hot).
// launch_bounds(256,8): cap VGPR<=64 -> 8 waves/SIMD.
// epilogue: h fp16 store + fused a1/a2 row-reductions (C/D layout m89).
// ---------------------------------------------------------------------------
__global__ __launch_bounds__(256, 8) void k1_mfma(
    const float* __restrict__ x, const ushort* __restrict__ WTfrag,
    const float* __restrict__ att,
    __half* __restrict__ h, float* __restrict__ a1, float* __restrict__ a2) {
  __shared__ __align__(16) ushort Ah[64 * 128];  // 16 KB

  int tid = threadIdx.x;
  int row0 = blockIdx.x * 64;

  // stage x tile: 64x128 f32 = 2048 float4; 8/thread; bf16; coalesced
#pragma unroll
  for (int it = 0; it < 8; ++it) {
    int i4 = it * 256 + tid;
    int row = i4 >> 5;
    int kq = i4 & 31;
    int grow = row0 + row;
    if (grow > N_NODES - 1) grow = N_NODES - 1;
    float4 v = ((const float4*)x)[(size_t)grow * 32 + kq];
    uint2 hv = make_uint2(f2bf(v.x) | (f2bf(v.y) << 16),
                          f2bf(v.z) | (f2bf(v.w) << 16));
    int idx = (row * 128 + kq * 4) ^ ((row & 7) << 3);
    *(uint2*)&Ah[idx] = hv;
  }
  __syncthreads();

  int w = tid >> 6, l = tid & 63;
  int ml = l & 15, kg = l >> 4;
  const bf16x8* __restrict__ Bf = (const bf16x8*)WTfrag;

  f32x4 acc[4];
#pragma unroll
  for (int nt = 0; nt < 4; ++nt) acc[nt] = (f32x4){0.f, 0.f, 0.f, 0.f};

#pragma unroll
  for (int ks = 0; ks < 4; ++ks) {
    int arow = w * 16 + ml;
    int aidx = (arow * 128 + ks * 32 + kg * 8) ^ ((arow & 7) << 3);
    bf16x8 a_h = *(const bf16x8*)&Ah[aidx];
#pragma unroll
    for (int nt = 0; nt < 4; ++nt) {
      bf16x8 b = Bf[(nt * 4 + ks) * 64 + l];  // coalesced 1KB/wave, L1-hot
      acc[nt] = __builtin_amdgcn_mfma_f32_16x16x32_bf16(a_h, b, acc[nt], 0, 0, 0);
    }
  }

  // epilogue: C/D layout col=lane&15, row=(lane>>4)*4+reg  [m89]
  float t1[4], t2[4];
#pragma unroll
  for (int nt = 0; nt < 4; ++nt) {
    t1[nt] = att[nt * 16 + ml];
    t2[nt] = att[OUT_DIM + nt * 16 + ml];
  }
#pragma unroll
  for (int r = 0; r < 4; ++r) {
    int drow = kg * 4 + r;
    int grow = row0 + w * 16 + drow;
    bool ok = grow < N_NODES;
    float p1 = 0.f, p2 = 0.f;
#pragma unroll
    for (int nt = 0; nt < 4; ++nt) {
      float d = acc[nt][r];
      if (ok) h[(size_t)grow * OUT_DIM + nt * 16 + ml] = __float2half(d);
      p1 = fmaf(d, t1[nt], p1);
      p2 = fmaf(d, t2[nt], p2);
    }
#pragma unroll
    for (int o = 1; o <= 8; o <<= 1) {
      p1 += __shfl_xor(p1, o, 64);
      p2 += __shfl_xor(p2, o, 64);
    }
    if (ml == 0 && ok) { a1[grow] = p1; a2[grow] = p2; }
  }
}

// ---------------------------------------------------------------------------
// K2: histogram + rank in ONE atomic, 8 edges/thread.
// ---------------------------------------------------------------------------
__global__ __launch_bounds__(256) void k2_rank(const int* __restrict__ dstp,
                                               int* __restrict__ deg,
                                               int* __restrict__ rank) {
  int t = blockIdx.x * 256 + threadIdx.x;
  if (t >= K2_T) return;
  int4 d0 = ((const int4*)dstp)[t * 2];
  int4 d1 = ((const int4*)dstp)[t * 2 + 1];
  int4 r0, r1;
  r0.x = atomicAdd(&deg[d0.x], 1);
  r0.y = atomicAdd(&deg[d0.y], 1);
  r0.z = atomicAdd(&deg[d0.z], 1);
  r0.w = atomicAdd(&deg[d0.w], 1);
  r1.x = atomicAdd(&deg[d1.x], 1);
  r1.y = atomicAdd(&deg[d1.y], 1);
  r1.z = atomicAdd(&deg[d1.z], 1);
  r1.w = atomicAdd(&deg[d1.w], 1);
  ((int4*)rank)[t * 2] = r0;
  ((int4*)rank)[t * 2 + 1] = r1;
}

// ---------------------------------------------------------------------------
// K3: LOCAL scan only (per 1024-node chunk) + chunk total -> bsum.
// No k3c pass: consumers (k4/k5) add the 49-entry bsum prefix themselves.
// ---------------------------------------------------------------------------
__global__ __launch_bounds__(256) void k3_scan(const int* __restrict__ deg,
                                               int* __restrict__ off,
                                               int* __restrict__ bsum) {
  __shared__ int sw[4];
  int tid = threadIdx.x, lane = tid & 63, wid = tid >> 6;
  int i4 = blockIdx.x * 256 + tid;
  int4 v = make_int4(0, 0, 0, 0);
  if (i4 < N4) v = ((const int4*)deg)[i4];
  int local = v.x + v.y + v.z + v.w;
  int incl = local;
#pragma unroll
  for (int o = 1; o < 64; o <<= 1) {
    int t = __shfl_up(incl, o, 64);
    if (lane >= o) incl += t;
  }
  if (lane == 63) sw[wid] = incl;
  __syncthreads();
  if (tid == 0) {
    int c = 0;
#pragma unroll
    for (int ww = 0; ww < 4; ++ww) { int t = sw[ww]; sw[ww] = c; c += t; }
    bsum[blockIdx.x] = c;
  }
  __syncthreads();
  int excl = incl - local + sw[wid];
  int4 o;
  o.x = excl; o.y = o.x + v.x; o.z = o.y + v.y; o.w = o.z + v.z;
  if (i4 < N4) ((int4*)off)[i4] = o;
}

// ---------------------------------------------------------------------------
// helper: per-block exclusive scan of bsum[49] into LDS sBX
// ---------------------------------------------------------------------------
__device__ __forceinline__ void scan_bsum_to_lds(const int* __restrict__ bsum,
                                                 int* sBX, int tid) {
  if (tid < 64) {
    int v = (tid < SCAN_NB) ? bsum[tid] : 0;
    int incl = v;
#pragma unroll
    for (int o = 1; o < 64; o <<= 1) {
      int t = __shfl_up(incl, o, 64);
      if (tid >= o) incl += t;
    }
    sBX[tid] = incl - v;  // exclusive chunk prefix
  }
  __syncthreads();
}

// ---------------------------------------------------------------------------
// K4: atomic-free scatter, 8 edges/thread:
// sedge[off_local[d] + sBX[d>>10] + rank] = {src, exp(leaky(a1[s]+a2[d]))}
// ---------------------------------------------------------------------------
__global__ __launch_bounds__(256) void k4_scatter(
    const int* __restrict__ src, const int* __restrict__ dstp,
    const int* __restrict__ rank, const int* __restrict__ bsum,
    const float* __restrict__ a1, const float* __restrict__ a2,
    const int* __restrict__ off, int2* __restrict__ sedge) {
  __shared__ int sBX[64];
  int tid = threadIdx.x;
  scan_bsum_to_lds(bsum, sBX, tid);

  int t = blockIdx.x * 256 + tid;
  if (t >= K4_T) return;
  int4 s0 = ((const int4*)src)[t * 2],  s1 = ((const int4*)src)[t * 2 + 1];
  int4 d0 = ((const int4*)dstp)[t * 2], d1 = ((const int4*)dstp)[t * 2 + 1];
  int4 r0 = ((const int4*)rank)[t * 2], r1 = ((const int4*)rank)[t * 2 + 1];
  int S[8] = {s0.x, s0.y, s0.z, s0.w, s1.x, s1.y, s1.z, s1.w};
  int D[8] = {d0.x, d0.y, d0.z, d0.w, d1.x, d1.y, d1.z, d1.w};
  int R[8] = {r0.x, r0.y, r0.z, r0.w, r1.x, r1.y, r1.z, r1.w};
  float A[8], B[8];
  int O[8];
#pragma unroll
  for (int q = 0; q < 8; ++q) {
    A[q] = a1[S[q]];
    B[q] = a2[D[q]];
    O[q] = off[D[q]];
  }
#pragma unroll
  for (int q = 0; q < 8; ++q) {
    float e = A[q] + B[q];
    e = e > 0.f ? e : 0.2f * e;  // leaky_relu 0.2
    // logits O(1): exp w/o max pass (softmax shift-invariant)
    int p = O[q] + sBX[D[q] >> 10] + R[q];
    sedge[p] = make_int2(S[q], __float_as_int(__expf(e)));
  }
}

// ---------------------------------------------------------------------------
// K5: per-node weighted aggregation + ELU. 8 lanes/node (uint4/lane),
// 8 nodes/wave, 8-edge unroll -> 64 row-gathers in flight per wave.
// ---------------------------------------------------------------------------
__global__ __launch_bounds__(256) void k5_agg(
    const int* __restrict__ off, const int* __restrict__ bsum,
    const int2* __restrict__ sedge,
    const __half* __restrict__ h, float* __restrict__ out) {
  __shared__ int sBX[64];
  int tid = threadIdx.x;
  scan_bsum_to_lds(bsum, sBX, tid);

  int g = tid >> 3, gl = tid & 7;
  int n = blockIdx.x * 32 + g;
  if (n >= N_NODES) return;
  int b = off[n] + sBX[n >> 10];
  int e = (n + 1 < N_NODES) ? (off[n + 1] + sBX[(n + 1) >> 10]) : N_EDGES;

  float sum = 0.f;
  float a0 = 0.f, a1_ = 0.f, a2_ = 0.f, a3 = 0.f;
  float a4 = 0.f, a5 = 0.f, a6 = 0.f, a7 = 0.f;
  const __half* __restrict__ hb = h;

#define K5_ACC(rr, ww)                                                        \
  {                                                                           \
    float2 f;                                                                 \
    f = __half22float2(__builtin_bit_cast(__half2, rr.x));                    \
    a0 = fmaf(ww, f.x, a0); a1_ = fmaf(ww, f.y, a1_);                         \
    f = __half22float2(__builtin_bit_cast(__half2, rr.y));                    \
    a2_ = fmaf(ww, f.x, a2_); a3 = fmaf(ww, f.y, a3);                         \
    f = __half22float2(__builtin_bit_cast(__half2, rr.z));                    \
    a4 = fmaf(ww, f.x, a4); a5 = fmaf(ww, f.y, a5);                           \
    f = __half22float2(__builtin_bit_cast(__half2, rr.w));                    \
    a6 = fmaf(ww, f.x, a6); a7 = fmaf(ww, f.y, a7);                           \
  }

  int j = b;
  for (; j + 7 < e; j += 8) {
    int2 s0 = sedge[j + 0], s1 = sedge[j + 1], s2 = sedge[j + 2], s3 = sedge[j + 3];
    int2 s4 = sedge[j + 4], s5 = sedge[j + 5], s6 = sedge[j + 6], s7 = sedge[j + 7];
    uint4 r0 = ((const uint4*)(hb + (size_t)s0.x * OUT_DIM))[gl];
    uint4 r1 = ((const uint4*)(hb + (size_t)s1.x * OUT_DIM))[gl];
    uint4 r2 = ((const uint4*)(hb + (size_t)s2.x * OUT_DIM))[gl];
    uint4 r3 = ((const uint4*)(hb + (size_t)s3.x * OUT_DIM))[gl];
    uint4 r4 = ((const uint4*)(hb + (size_t)s4.x * OUT_DIM))[gl];
    uint4 r5 = ((const uint4*)(hb + (size_t)s5.x * OUT_DIM))[gl];
    uint4 r6 = ((const uint4*)(hb + (size_t)s6.x * OUT_DIM))[gl];
    uint4 r7 = ((const uint4*)(hb + (size_t)s7.x * OUT_DIM))[gl];
    float w0 = __int_as_float(s0.y), w1 = __int_as_float(s1.y);
    float w2 = __int_as_float(s2.y), w3 = __int_as_float(s3.y);
    float w4 = __int_as_float(s4.y), w5 = __int_as_float(s5.y);
    float w6 = __int_as_float(s6.y), w7 = __int_as_float(s7.y);
    sum += ((w0 + w1) + (w2 + w3)) + ((w4 + w5) + (w6 + w7));
    K5_ACC(r0, w0); K5_ACC(r1, w1); K5_ACC(r2, w2); K5_ACC(r3, w3);
    K5_ACC(r4, w4); K5_ACC(r5, w5); K5_ACC(r6, w6); K5_ACC(r7, w7);
  }
  for (; j + 3 < e; j += 4) {
    int2 s0 = sedge[j + 0], s1 = sedge[j + 1], s2 = sedge[j + 2], s3 = sedge[j + 3];
    uint4 r0 = ((const uint4*)(hb + (size_t)s0.x * OUT_DIM))[gl];
    uint4 r1 = ((const uint4*)(hb + (size_t)s1.x * OUT_DIM))[gl];
    uint4 r2 = ((const uint4*)(hb + (size_t)s2.x * OUT_DIM))[gl];
    uint4 r3 = ((const uint4*)(hb + (size_t)s3.x * OUT_DIM))[gl];
    float w0 = __int_as_float(s0.y), w1 = __int_as_float(s1.y);
    float w2 = __int_as_float(s2.y), w3 = __int_as_float(s3.y);
    sum += (w0 + w1) + (w2 + w3);
    K5_ACC(r0, w0); K5_ACC(r1, w1); K5_ACC(r2, w2); K5_ACC(r3, w3);
  }
  for (; j < e; ++j) {
    int2 s0 = sedge[j];
    uint4 r0 = ((const uint4*)(hb + (size_t)s0.x * OUT_DIM))[gl];
    float w0 = __int_as_float(s0.y);
    sum += w0;
    K5_ACC(r0, w0);
  }

  float inv = (e > b) ? 1.f / sum : 0.f;
  a0 *= inv; a1_ *= inv; a2_ *= inv; a3 *= inv;
  a4 *= inv; a5 *= inv; a6 *= inv; a7 *= inv;
  float4 o0, o1;
  o0.x = a0 > 0.f ? a0 : (__expf(a0) - 1.f);
  o0.y = a1_ > 0.f ? a1_ : (__expf(a1_) - 1.f);
  o0.z = a2_ > 0.f ? a2_ : (__expf(a2_) - 1.f);
  o0.w = a3 > 0.f ? a3 : (__expf(a3) - 1.f);
  o1.x = a4 > 0.f ? a4 : (__expf(a4) - 1.f);
  o1.y = a5 > 0.f ? a5 : (__expf(a5) - 1.f);
  o1.z = a6 > 0.f ? a6 : (__expf(a6) - 1.f);
  o1.w = a7 > 0.f ? a7 : (__expf(a7) - 1.f);
  float4* ob = (float4*)(out + (size_t)n * OUT_DIM);
  ob[gl * 2] = o0;
  ob[gl * 2 + 1] = o1;
}

// ---------------------------------------------------------------------------
extern "C" void kernel_launch(void* const* d_in, const int* in_sizes, int n_in,
                              void* d_out, int out_size, void* d_ws, size_t ws_size,
                              hipStream_t stream) {
  const float* x   = (const float*)d_in[0];
  const int*   ei  = (const int*)d_in[1];   // [2, E]
  const float* W   = (const float*)d_in[2];
  const float* att = (const float*)d_in[3];
  float* out = (float*)d_out;

  char* p = (char*)d_ws;
  __half* h  = (__half*)p;  p += (size_t)N_NODES * OUT_DIM * sizeof(__half);  // 6.4 MB
  float* a1  = (float*)p;   p += (size_t)N_NODES * sizeof(float);
  float* a2  = (float*)p;   p += (size_t)N_NODES * sizeof(float);
  int*   deg = (int*)p;     p += (size_t)N_NODES * sizeof(int);
  int*   off = (int*)p;     p += (size_t)(N_NODES + 4) * sizeof(int);
  int*   rank = (int*)p;    p += (size_t)N_EDGES * sizeof(int);               // 3.2 MB
  int2*  sedge = (int2*)p;  p += (size_t)N_EDGES * sizeof(int2);              // 6.4 MB
  int*   bsum = (int*)p;    p += 64 * sizeof(int);
  ushort* WTfrag = (ushort*)p; p += (size_t)OUT_DIM * IN_DIM * sizeof(ushort);

  const int* src  = ei;
  const int* dstp = ei + N_EDGES;

  k0_prep<<<SCAN_NB, 256, 0, stream>>>(W, deg, WTfrag);
  k2_rank<<<(K2_T + 255) / 256, 256, 0, stream>>>(dstp, deg, rank);
  k1_mfma<<<GEMM_NB, 256, 0, stream>>>(x, WTfrag, att, h, a1, a2);
  k3_scan<<<SCAN_NB, 256, 0, stream>>>(deg, off, bsum);
  k4_scatter<<<(K4_T + 255) / 256, 256, 0, stream>>>(src, dstp, rank, bsum, a1, a2, off, sedge);
  k5_agg<<<(N_NODES + 31) / 32, 256, 0, stream>>>(off, bsum, sedge, h, out);
}